// Round 3
// baseline (246.311 us; speedup 1.0000x reference)
//
#include <hip/hip_runtime.h>

// Trilinear resample (identity affine) of (B=4, D=64, H=64, W=64, C=32) fp32.
// Separable form: out[m] = in[max(m-1,0)]*(1-f) + in[m]*f, f = frac(m*62/63), per axis.
// v2: 2x2x2 output voxels per thread (one float4 channel-quad each) via
// separable x->y->z register blending: 27 loads per 8 outputs (3.4/output vs 8/output
// in v1). Attacks the L1 line-touch / miss-bandwidth bound (v1: 13.4 TB/s delivered
// load traffic, HBM only 42% busy, FETCH already minimal).
// Stores nontemporal (output never re-read), block swizzle keeps row reuse per-XCD.
// v2b: nontemporal builtin needs a native vector type -> bit-cast via ext_vector_type.

#define C4 8  // float4 quads per voxel (32 channels)

typedef float f4raw __attribute__((ext_vector_type(4)));

__device__ __forceinline__ void nt_store(float4 v, float4* p) {
    __builtin_nontemporal_store(*reinterpret_cast<f4raw*>(&v),
                                reinterpret_cast<f4raw*>(p));
}

__device__ __forceinline__ float4 f4lerp(float4 a, float wa, float4 b, float wb) {
    float4 r;
    r.x = fmaf(a.x, wa, b.x * wb);
    r.y = fmaf(a.y, wa, b.y * wb);
    r.z = fmaf(a.z, wa, b.z * wb);
    r.w = fmaf(a.w, wa, b.w * wb);
    return r;
}

__device__ __forceinline__ float4 f4scale(float4 a, float w) {
    float4 r;
    r.x = a.x * w; r.y = a.y * w; r.z = a.z * w; r.w = a.w * w;
    return r;
}

__device__ __forceinline__ void f4acc(float4& c, float4 a, float w) {
    c.x = fmaf(a.x, w, c.x);
    c.y = fmaf(a.y, w, c.y);
    c.z = fmaf(a.z, w, c.z);
    c.w = fmaf(a.w, w, c.w);
}

__global__ __launch_bounds__(256) void trilerp_kernel(
    const float4* __restrict__ in, float4* __restrict__ out) {
    // XCD-contiguous swizzle: gridDim.x = 4096, divisible by 8 -> bijective.
    int bid  = (int)blockIdx.x;
    int sbid = (bid & 7) * ((int)gridDim.x >> 3) + (bid >> 3);
    int t    = sbid * 256 + (int)threadIdx.x;

    int cq = t & 7;          // channel quad 0..7
    int kp = (t >> 3) & 31;  // x-pair
    int j2 = (t >> 8) & 31;  // y-pair
    int i2 = (t >> 13) & 31; // z-pair
    int b  = t >> 18;        // batch

    int x1 = kp << 1, x2 = x1 + 1, x0 = (x1 > 0) ? x1 - 1 : 0;
    int y1 = j2 << 1, y2 = y1 + 1, y0 = (y1 > 0) ? y1 - 1 : 0;
    int z1 = i2 << 1, z2 = z1 + 1, z0 = (z1 > 0) ? z1 - 1 : 0;

    const float s = 62.0f / 63.0f;
    // f(m) = frac(m*s); weight of elem[m-1] is (1-f), of elem[m] is f.
    float tx0 = (float)x1 * s; float fx0 = tx0 - (float)(int)tx0; float gx0 = 1.0f - fx0;
    float tx1 = (float)x2 * s; float fx1 = tx1 - (float)(int)tx1; float gx1 = 1.0f - fx1;
    float ty0 = (float)y1 * s; float fy0 = ty0 - (float)(int)ty0; float gy0 = 1.0f - fy0;
    float ty1 = (float)y2 * s; float fy1 = ty1 - (float)(int)ty1; float gy1 = 1.0f - fy1;
    float tz0 = (float)z1 * s; float fz0 = tz0 - (float)(int)tz0; float gz0 = 1.0f - fz0;
    float tz1 = (float)z2 * s; float fz1 = tz1 - (float)(int)tz1; float gz1 = 1.0f - fz1;

    // quad index = (((b*64+z)*64+y)*64+x)*8 + cq
    int bb  = b << 21;
    int ry0 = y0 << 9, ry1 = y1 << 9, ry2 = y2 << 9;
    int xo0 = (x0 << 3) + cq, xo1 = (x1 << 3) + cq, xo2 = (x2 << 3) + cq;

    float4 by00, by01, by10, by11;  // [y-out][x-out], xy-blended plane values

#define PLANE(ZP) do {                                                         \
        const float4* __restrict__ P = in + (bb + ((ZP) << 15));               \
        float4 e0a = P[ry0 + xo0], e0b = P[ry0 + xo1], e0c = P[ry0 + xo2];     \
        float4 e1a = P[ry1 + xo0], e1b = P[ry1 + xo1], e1c = P[ry1 + xo2];     \
        float4 e2a = P[ry2 + xo0], e2b = P[ry2 + xo1], e2c = P[ry2 + xo2];     \
        float4 bx0l = f4lerp(e0a, gx0, e0b, fx0);                              \
        float4 bx0r = f4lerp(e0b, gx1, e0c, fx1);                              \
        float4 bx1l = f4lerp(e1a, gx0, e1b, fx0);                              \
        float4 bx1r = f4lerp(e1b, gx1, e1c, fx1);                              \
        float4 bx2l = f4lerp(e2a, gx0, e2b, fx0);                              \
        float4 bx2r = f4lerp(e2b, gx1, e2c, fx1);                              \
        by00 = f4lerp(bx0l, gy0, bx1l, fy0);                                   \
        by01 = f4lerp(bx0r, gy0, bx1r, fy0);                                   \
        by10 = f4lerp(bx1l, gy1, bx2l, fy1);                                   \
        by11 = f4lerp(bx1r, gy1, bx2r, fy1);                                   \
    } while (0)

    // plane z0: contributes to out z=z1 with weight gz0
    PLANE(z0);
    float4 o000 = f4scale(by00, gz0), o001 = f4scale(by01, gz0);
    float4 o010 = f4scale(by10, gz0), o011 = f4scale(by11, gz0);

    // plane z1: out z1 += fz0*by ; out z2 = gz1*by
    PLANE(z1);
    f4acc(o000, by00, fz0); f4acc(o001, by01, fz0);
    f4acc(o010, by10, fz0); f4acc(o011, by11, fz0);
    float4 o100 = f4scale(by00, gz1), o101 = f4scale(by01, gz1);
    float4 o110 = f4scale(by10, gz1), o111 = f4scale(by11, gz1);

    // plane z2: out z2 += fz1*by
    PLANE(z2);
    f4acc(o100, by00, fz1); f4acc(o101, by01, fz1);
    f4acc(o110, by10, fz1); f4acc(o111, by11, fz1);

#undef PLANE

    int base = bb + (y1 << 9) + (x1 << 3) + cq;
    int zb1  = z1 << 15, zb2 = z2 << 15;
    nt_store(o000, &out[base + zb1]);
    nt_store(o001, &out[base + zb1 + 8]);
    nt_store(o010, &out[base + zb1 + 512]);
    nt_store(o011, &out[base + zb1 + 520]);
    nt_store(o100, &out[base + zb2]);
    nt_store(o101, &out[base + zb2 + 8]);
    nt_store(o110, &out[base + zb2 + 512]);
    nt_store(o111, &out[base + zb2 + 520]);
}

extern "C" void kernel_launch(void* const* d_in, const int* in_sizes, int n_in,
                              void* d_out, int out_size, void* d_ws, size_t ws_size,
                              hipStream_t stream) {
    const float4* in = (const float4*)d_in[0];
    float4* out = (float4*)d_out;

    // threads = 4 batches * 32^3 pair-voxels * 8 quads = 2^20
    const int total = 4 * 32 * 32 * 32 * C4;
    const int block = 256;
    const int grid  = total / block;  // 4096

    trilerp_kernel<<<grid, block, 0, stream>>>(in, out);
}